// Round 11
// baseline (632.349 us; speedup 1.0000x reference)
//
#include <hip/hip_runtime.h>

using u16 = unsigned short;
using bf16x8 = __attribute__((ext_vector_type(8))) short;
using f32x4 = __attribute__((ext_vector_type(4))) float;
using f32x16 = __attribute__((ext_vector_type(16))) float;

__device__ __forceinline__ u16 f2bf(float f) {
  unsigned x = __float_as_uint(f);
  x += 0x7fffu + ((x >> 16) & 1u);
  return (u16)(x >> 16);
}

__device__ __forceinline__ void gl2lds16(const u16* g, u16* l) {
  __builtin_amdgcn_global_load_lds(
      (const __attribute__((address_space(1))) unsigned int*)g,
      (__attribute__((address_space(3))) unsigned int*)l, 16, 0, 0);
}

// ---------------- consolidated cast + transposes (1 launch) ----------------
// casts: x->Krep, Wq->Wqb, Wk->Wkb, Wv->Wvb, W1->W1b (plain; FFN collapse
// needs W1 row-major). transposes: x^T->XT, Wo->WoT, W2->W2T.
__global__ __launch_bounds__(256) void cvt_all(
    const float* __restrict__ x, u16* __restrict__ Krep, u16* __restrict__ XT,
    const float* __restrict__ Wq, const float* __restrict__ Wk,
    const float* __restrict__ Wv, const float* __restrict__ Wo,
    const float* __restrict__ W1, const float* __restrict__ W2,
    u16* __restrict__ Wqb, u16* __restrict__ Wkb, u16* __restrict__ Wvb,
    u16* __restrict__ WoT, u16* __restrict__ W1b, u16* __restrict__ W2T)
{
  int b = blockIdx.x, tid = threadIdx.x;
  if (b < 11264) {
    const float* s; u16* d; int i;
    if (b < 4096)       { s = x;  d = Krep; i = b * 1024 + tid * 4; }
    else if (b < 6144)  { s = Wq; d = Wqb;  i = (b - 4096) * 1024 + tid * 4; }
    else if (b < 8192)  { s = Wk; d = Wkb;  i = (b - 6144) * 1024 + tid * 4; }
    else if (b < 10240) { s = Wv; d = Wvb;  i = (b - 8192) * 1024 + tid * 4; }
    else                { s = W1; d = W1b;  i = (b - 10240) * 1024 + tid * 4; }
    float4 v = *(const float4*)(s + i);
    ushort4 o;
    o.x = f2bf(v.x); o.y = f2bf(v.y); o.z = f2bf(v.z); o.w = f2bf(v.w);
    *(ushort4*)(d + i) = o;
    return;
  }
  __shared__ float T[32][33];
  const float* s; u16* d; int K, N, k0, n0;
  int i = b - 11264;
  if (i < 4096) {
    int b8 = i >> 9, j = i & 511;
    s = x + (size_t)b8 * 524288; d = XT + (size_t)b8 * 524288;
    K = 1024; N = 512; n0 = (j % 16) * 32; k0 = (j / 16) * 32;
  } else if (i < 6144) {
    int j = i - 4096;
    s = Wo; d = WoT; K = 4096; N = 512; n0 = (j % 16) * 32; k0 = (j / 16) * 32;
  } else {
    int j = i - 6144;
    s = W2; d = W2T; K = 2048; N = 512; n0 = (j % 16) * 32; k0 = (j / 16) * 32;
  }
  int r = tid >> 3, c4 = (tid & 7) << 2;
  float4 v = *(const float4*)(s + (size_t)(k0 + r) * N + n0 + c4);
  T[r][c4 + 0] = v.x; T[r][c4 + 1] = v.y; T[r][c4 + 2] = v.z; T[r][c4 + 3] = v.w;
  __syncthreads();
  ushort4 o;
  o.x = f2bf(T[c4 + 0][r]); o.y = f2bf(T[c4 + 1][r]);
  o.z = f2bf(T[c4 + 2][r]); o.w = f2bf(T[c4 + 3][r]);
  *(ushort4*)(d + (size_t)(n0 + r) * K + k0 + c4) = o;
}

// ---------------- w = Wk . bq per head (wave per output row) ---------------
__global__ __launch_bounds__(256) void wk_bias(
    const float* __restrict__ Wk, const float* __restrict__ bq,
    float* __restrict__ wbuf)
{
  int r = blockIdx.x * 4 + (threadIdx.x >> 6);
  int lane = threadIdx.x & 63;
  int h = r >> 9, a = r & 511;
  const float* row = Wk + ((size_t)h * 512 + a) * 512 + lane * 8;
  const float* bqp = bq + h * 512 + lane * 8;
  float4 w0 = *(const float4*)row, w1 = *(const float4*)(row + 4);
  float4 b0 = *(const float4*)bqp, b1 = *(const float4*)(bqp + 4);
  float s = w0.x * b0.x + w0.y * b0.y + w0.z * b0.z + w0.w * b0.w +
            w1.x * b1.x + w1.y * b1.y + w1.z * b1.z + w1.w * b1.w;
  #pragma unroll
  for (int off = 1; off < 64; off <<= 1) s += __shfl_xor(s, off);
  if (lane == 0) wbuf[r] = s;
}

// ---------- out[e] = c[e] + sum_k v[k]*W[k*512+e], K = kc*16 ---------------
__global__ __launch_bounds__(256) void vec_fold(
    const float* __restrict__ v, const float* __restrict__ W,
    const float* __restrict__ c, float* __restrict__ out, int kc)
{
  __shared__ float part[16][17];
  int ei = threadIdx.x & 15, ch = threadIdx.x >> 4;
  int e = blockIdx.x * 16 + ei;
  float s = 0.f;
  for (int k = ch * kc; k < ch * kc + kc; k++)
    s += v[k] * W[(size_t)k * 512 + e];
  part[ei][ch] = s;
  __syncthreads();
  if (threadIdx.x < 16) {
    float t = c[blockIdx.x * 16 + threadIdx.x];
    #pragma unroll
    for (int cc = 0; cc < 16; cc++) t += part[threadIdx.x][cc];
    out[blockIdx.x * 16 + threadIdx.x] = t;
  }
}

// ---------------- generic bf16 GEMM, 2-phase double-buffered ----------------
template<int BM>
__global__ __launch_bounds__(256) void gemm_bt(
    const u16* __restrict__ A, const u16* __restrict__ Bt,
    const float* __restrict__ bias, void* __restrict__ Cout,
    int M, int N, int K, int lda, int ldb, long long kzoff,
    long long sBz, long long sbz, long long sCzBytes, int out_mode)
{
  constexpr int MT = BM / 32;
  constexpr int TILE = BM * 32 + 128 * 32;     // u16 per buffer
  __shared__ __align__(16) u16 smem[2 * TILE];
  const f32x4 zero4 = {0.f, 0.f, 0.f, 0.f};

  const u16* Ap = A + (size_t)blockIdx.z * (size_t)kzoff;
  const u16* Bp = Bt + (size_t)blockIdx.z * (size_t)(sBz + kzoff);
  const float* biasp = bias ? bias + (size_t)blockIdx.z * sbz : nullptr;
  char* Cp = (char*)Cout + (size_t)blockIdx.z * sCzBytes;

  // XCD-chunk swizzle of the (x,y) plane (T1; P % 8 == 0 for all grids)
  int P = gridDim.x * gridDim.y;
  int p = blockIdx.x + gridDim.x * blockIdx.y;
  int f = (p & 7) * (P >> 3) + (p >> 3);
  int bx = f % gridDim.x, by = f / gridDim.x;

  int tid = threadIdx.x;
  int lane = tid & 63, wave = tid >> 6;
  int m = lane & 15, quad = lane >> 4;
  int wm = (wave >> 1) * (BM / 2), wn = (wave & 1) * 64;
  int m0 = by * BM, n0 = bx * 128;
  int lr = lane >> 2, lc = (lane & 3) << 3;

  auto stage = [&](int buf, int k0) {
    u16* As = smem + buf * TILE;
    u16* Bs = As + BM * 32;
    #pragma unroll
    for (int i = 0; i < BM / 64; i++) {
      int rb = i * 64 + wave * 16;
      gl2lds16(Ap + (size_t)(m0 + rb + lr) * lda + k0 + lc, &As[rb * 32]);
    }
    #pragma unroll
    for (int i = 0; i < 2; i++) {
      int rb = i * 64 + wave * 16;
      gl2lds16(Bp + (size_t)(n0 + rb + lr) * ldb + k0 + lc, &Bs[rb * 32]);
    }
  };

  f32x4 acc[MT][4];
  #pragma unroll
  for (int i = 0; i < MT; i++)
    #pragma unroll
    for (int j = 0; j < 4; j++) acc[i][j] = zero4;

  stage(0, 0);
  asm volatile("s_waitcnt vmcnt(0)" ::: "memory");
  __builtin_amdgcn_s_barrier();

  int nt = K >> 5;
  int cur = 0;
  for (int t = 0; t < nt; t++) {
    if (t + 1 < nt) stage(cur ^ 1, (t + 1) << 5);   // DMA flies under MFMAs

    u16* As = smem + cur * TILE;
    u16* Bs = As + BM * 32;
    bf16x8 af[MT], bfr[4];
    #pragma unroll
    for (int tt = 0; tt < MT; tt++)
      af[tt] = *(const bf16x8*)&As[(wm + tt * 16 + m) * 32 + quad * 8];
    #pragma unroll
    for (int tt = 0; tt < 4; tt++)
      bfr[tt] = *(const bf16x8*)&Bs[(wn + tt * 16 + m) * 32 + quad * 8];
    #pragma unroll
    for (int mt = 0; mt < MT; mt++)
      #pragma unroll
      for (int nt2 = 0; nt2 < 4; nt2++)
        acc[mt][nt2] = __builtin_amdgcn_mfma_f32_16x16x32_bf16(af[mt], bfr[nt2],
                                                               acc[mt][nt2], 0, 0, 0);
    asm volatile("s_waitcnt vmcnt(0)" ::: "memory");
    __builtin_amdgcn_s_barrier();
    cur ^= 1;
  }

  if (out_mode == 2) {
    u16* Ts = smem;
    int b2 = m0 >> 10, t20 = m0 & 1023;
    int half = wave >> 1;
    #pragma unroll
    for (int mt = 0; mt < MT; mt++) {
      #pragma unroll
      for (int nt2 = 0; nt2 < 4; nt2++) {
        int colc = wn + nt2 * 16 + m;
        float bb = biasp ? biasp[n0 + colc] : 0.f;
        #pragma unroll
        for (int r = 0; r < 4; r++)
          Ts[colc * 40 + half * 16 + quad * 4 + r] = f2bf(acc[mt][nt2][r] + bb);
      }
      __syncthreads();
      #pragma unroll
      for (int it = 0; it < 2; it++) {
        int c = (tid >> 2) + 64 * it;
        int j = tid & 3;
        bf16x8 v = *(const bf16x8*)&Ts[c * 40 + j * 8];
        int tg = t20 + (j >> 1) * (BM / 2) + mt * 16 + (j & 1) * 8;
        *(bf16x8*)((u16*)Cp + ((size_t)b2 * 512 + n0 + c) * 1024 + tg) = v;
      }
      __syncthreads();
    }
    return;
  }

  #pragma unroll
  for (int nt2 = 0; nt2 < 4; nt2++) {
    int col = n0 + wn + nt2 * 16 + m;
    float bb = biasp ? biasp[col] : 0.f;
    #pragma unroll
    for (int mt = 0; mt < MT; mt++) {
      #pragma unroll
      for (int r = 0; r < 4; r++) {
        int row = m0 + wm + mt * 16 + quad * 4 + r;
        float v = acc[mt][nt2][r] + bb;
        if (out_mode == 1) {
          ((u16*)Cp)[(size_t)row * N + col] = f2bf(v);
        } else {
          ((float*)Cp)[(size_t)row * N + col] = v;
        }
      }
    }
  }
}

// ---------------- T projection only (2-phase double-buffered) ---------------
__global__ __launch_bounds__(256) void gemm_t8(
    const u16* __restrict__ A, const u16* __restrict__ Mt,
    const float* __restrict__ wbuf, u16* __restrict__ Tg)
{
  constexpr int TILE = 8192;
  __shared__ __align__(16) u16 smem[2 * TILE];
  const f32x4 zero4 = {0.f, 0.f, 0.f, 0.f};

  int h = blockIdx.z;
  const u16* Bp = Mt + (size_t)h * 262144;
  const float* biasp = wbuf + h * 512;
  u16* Og = Tg + (size_t)h * 4194304;

  int P = gridDim.x * gridDim.y;
  int p = blockIdx.x + gridDim.x * blockIdx.y;
  int f = (p & 7) * (P >> 3) + (p >> 3);
  int bx = f % gridDim.x, by = f / gridDim.x;

  int tid = threadIdx.x;
  int lane = tid & 63, wave = tid >> 6;
  int m = lane & 15, quad = lane >> 4;
  int wm = (wave >> 1) * 64, wn = (wave & 1) * 64;
  int m0 = by * 128, n0 = bx * 128;
  int lr = lane >> 2, lc = (lane & 3) << 3;

  auto stage = [&](int buf, int k0) {
    u16* As = smem + buf * TILE;
    u16* Bs = As + 4096;
    #pragma unroll
    for (int i = 0; i < 2; i++) {
      int rb = i * 64 + wave * 16;
      gl2lds16(A + (size_t)(m0 + rb + lr) * 512 + k0 + lc, &As[rb * 32]);
      gl2lds16(Bp + (size_t)(n0 + rb + lr) * 512 + k0 + lc, &Bs[rb * 32]);
    }
  };

  f32x4 acc[4][4];
  #pragma unroll
  for (int i = 0; i < 4; i++)
    #pragma unroll
    for (int j = 0; j < 4; j++) acc[i][j] = zero4;

  stage(0, 0);
  asm volatile("s_waitcnt vmcnt(0)" ::: "memory");
  __builtin_amdgcn_s_barrier();

  int cur = 0;
  for (int t = 0; t < 16; t++) {
    if (t + 1 < 16) stage(cur ^ 1, (t + 1) << 5);

    u16* As = smem + cur * TILE;
    u16* Bs = As + 4096;
    bf16x8 af[4], bfr[4];
    #pragma unroll
    for (int tt = 0; tt < 4; tt++) {
      af[tt]  = *(const bf16x8*)&As[(wm + tt * 16 + m) * 32 + quad * 8];
      bfr[tt] = *(const bf16x8*)&Bs[(wn + tt * 16 + m) * 32 + quad * 8];
    }
    #pragma unroll
    for (int mt = 0; mt < 4; mt++)
      #pragma unroll
      for (int nt = 0; nt < 4; nt++)
        acc[mt][nt] = __builtin_amdgcn_mfma_f32_16x16x32_bf16(af[mt], bfr[nt],
                                                              acc[mt][nt], 0, 0, 0);
    asm volatile("s_waitcnt vmcnt(0)" ::: "memory");
    __builtin_amdgcn_s_barrier();
    cur ^= 1;
  }

  #pragma unroll
  for (int nt = 0; nt < 4; nt++) {
    int col = n0 + wn + nt * 16 + m;
    float bb = biasp[col];
    #pragma unroll
    for (int mt = 0; mt < 4; mt++) {
      #pragma unroll
      for (int r = 0; r < 4; r++) {
        int row = m0 + wm + mt * 16 + quad * 4 + r;
        Og[(size_t)row * 512 + col] = f2bf(acc[mt][nt][r] + bb);
      }
    }
  }
}

// ---------------- flash attention (R9-proven, unchanged) --------------------
__global__ __launch_bounds__(256, 2) void attn_kernel(
    const u16* __restrict__ Tg, const u16* __restrict__ Krep,
    const u16* __restrict__ XT, u16* __restrict__ Oc, int h0)
{
  __shared__ __align__(16) u16 Kt[32][520];   // 33,280 B
  __shared__ __align__(16) u16 Vt[512 * 32];  // 32,768 B (chunk-XOR swizzled)
  __shared__ __align__(16) u16 Pl[64][40];    //  5,120 B
  __shared__ float lred[64];
  const f32x4 zero4 = {0.f, 0.f, 0.f, 0.f};
  const f32x16 zero16 = {0.f,0.f,0.f,0.f,0.f,0.f,0.f,0.f,
                         0.f,0.f,0.f,0.f,0.f,0.f,0.f,0.f};

  int b = blockIdx.x, qb = blockIdx.y, z = blockIdx.z;
  int h = h0 + z;

  size_t hb = ((size_t)z * 8 + b) * (size_t)(1024 * 512);
  const u16* Tp = Tg + hb;
  const u16* Kp = Krep + (size_t)b * (size_t)(1024 * 512); // x slab (K)
  const u16* Vp = XT + (size_t)b * (size_t)(512 * 1024);   // x^T slab ("V")

  int tid = threadIdx.x, lane = tid & 63, wave = tid >> 6;
  int m = lane & 15, quad = lane >> 4;         // QK roles (16x16)
  int l31 = lane & 31, hi = lane >> 5;         // PV roles (32x32)
  int qh = wave >> 1, dh = wave & 1;
  int q0 = qb * 64 + wave * 16;

  int vr = lane >> 2;
  int vc = (((lane & 3) ^ ((lane >> 3) & 3)) << 3);
  int vswz = (l31 >> 1) & 3;

  bf16x8 aq[16];
  #pragma unroll
  for (int kc = 0; kc < 16; kc++)
    aq[kc] = *(const bf16x8*)(Tp + (size_t)(q0 + m) * 512 + kc * 32 + quad * 8);

  f32x16 o[8];
  #pragma unroll
  for (int dt = 0; dt < 8; dt++) o[dt] = zero16;
  float lsum_acc[4] = {0.f, 0.f, 0.f, 0.f};
  const float scale = 0.04419417382415922f;

  // prologue: stage tile 0
  #pragma unroll
  for (int r = 0; r < 8; r++) {
    int row = wave * 8 + r;
    gl2lds16(Kp + (size_t)row * 512 + lane * 8, &Kt[row][0]);
  }
  #pragma unroll
  for (int j = 0; j < 8; j++) {
    int rb = wave * 128 + j * 16;
    gl2lds16(Vp + (size_t)(rb + vr) * 1024 + vc, &Vt[rb * 32]);
  }

  for (int kt = 0; kt < 32; kt++) {
    // ---- BAR-A: K(kt) complete everywhere ----
    asm volatile("s_waitcnt vmcnt(8)" ::: "memory");
    __builtin_amdgcn_sched_barrier(0);
    __builtin_amdgcn_s_barrier();
    __builtin_amdgcn_sched_barrier(0);

    // ---- QK ----
    f32x4 s0 = zero4, s1 = zero4;
    #pragma unroll
    for (int kc = 0; kc < 16; kc++) {
      bf16x8 bk0 = *(const bf16x8*)&Kt[m][kc * 32 + quad * 8];
      bf16x8 bk1 = *(const bf16x8*)&Kt[m + 16][kc * 32 + quad * 8];
      s0 = __builtin_amdgcn_mfma_f32_16x16x32_bf16(aq[kc], bk0, s0, 0, 0, 0);
      s1 = __builtin_amdgcn_mfma_f32_16x16x32_bf16(aq[kc], bk1, s1, 0, 0, 0);
    }

    // ---- exp, P write, per-lane lsum partial ----
    #pragma unroll
    for (int r = 0; r < 4; r++) {
      float e0 = __expf(s0[r] * scale);
      float e1 = __expf(s1[r] * scale);
      u16 p0 = f2bf(e0), p1 = f2bf(e1);
      int prow = wave * 16 + quad * 4 + r;
      Pl[prow][m] = p0;
      Pl[prow][m + 16] = p1;
      lsum_acc[r] += __uint_as_float((unsigned)p0 << 16) +
                     __uint_as_float((unsigned)p1 << 16);
    }

    // ---- BAR-B: V(kt) ready + P visible + Kt free ----
    asm volatile("s_waitcnt vmcnt(0) lgkmcnt(0)" ::: "memory");
    __builtin_amdgcn_sched_barrier(0);
    __builtin_amdgcn_s_barrier();
    __builtin_amdgcn_sched_barrier(0);

    if (kt < 31) {                 // K(kt+1) DMA flies under PV
      int kr1 = (kt + 1) * 32;
      #pragma unroll
      for (int r = 0; r < 8; r++) {
        int row = wave * 8 + r;
        gl2lds16(Kp + (size_t)(kr1 + row) * 512 + lane * 8, &Kt[row][0]);
      }
    }

    // ---- PV: 32x32x16 ----
    const u16* PlRow = &Pl[qh * 32 + l31][0];
    #pragma unroll
    for (int ks = 0; ks < 2; ks++) {
      bf16x8 pa = *(const bf16x8*)(PlRow + ks * 16 + hi * 8);
      #pragma unroll
      for (int dt = 0; dt < 8; dt++) {
        int rr = dh * 256 + dt * 32 + l31;
        int cc2 = (((ks * 2 + hi) ^ vswz) << 3);
        bf16x8 bv = *(const bf16x8*)&Vt[rr * 32 + cc2];
        o[dt] = __builtin_amdgcn_mfma_f32_32x32x16_bf16(pa, bv, o[dt], 0, 0, 0);
      }
    }

    // ---- BAR-C: PV reads delivered; Vt, Pl free ----
    asm volatile("s_waitcnt lgkmcnt(0)" ::: "memory");
    __builtin_amdgcn_sched_barrier(0);
    __builtin_amdgcn_s_barrier();
    __builtin_amdgcn_sched_barrier(0);

    if (kt < 31) {                 // V(kt+1) DMA flies under next QK
      int kr1 = (kt + 1) * 32;
      #pragma unroll
      for (int j = 0; j < 8; j++) {
        int rb = wave * 128 + j * 16;
        gl2lds16(Vp + (size_t)(rb + vr) * 1024 + kr1 + vc, &Vt[rb * 32]);
      }
    }
  }

  // ---- deferred lsum reduce (once, not per-kt) ----
  #pragma unroll
  for (int r = 0; r < 4; r++) {
    float t = lsum_acc[r];
    t += __shfl_xor(t, 1); t += __shfl_xor(t, 2);
    t += __shfl_xor(t, 4); t += __shfl_xor(t, 8);
    lsum_acc[r] = t;
  }
  if (m == 0) {
    #pragma unroll
    for (int r = 0; r < 4; r++)
      lred[wave * 16 + quad * 4 + r] = lsum_acc[r];
  }
  __syncthreads();

  float linv[16];
  #pragma unroll
  for (int g = 0; g < 4; g++) {
    float4 t = *(const float4*)&lred[qh * 32 + 8 * g + 4 * hi];
    linv[4 * g + 0] = 1.f / t.x; linv[4 * g + 1] = 1.f / t.y;
    linv[4 * g + 2] = 1.f / t.z; linv[4 * g + 3] = 1.f / t.w;
  }

  size_t obase = (size_t)b * 1024 + qb * 64 + qh * 32;
  #pragma unroll
  for (int dt = 0; dt < 8; dt++) {
    int dcol = dh * 256 + dt * 32 + l31;
    #pragma unroll
    for (int reg = 0; reg < 16; reg++) {
      int rowq = (reg & 3) + 8 * (reg >> 2) + 4 * hi;
      Oc[((obase + rowq) * 8 + h) * 512 + dcol] = f2bf(o[dt][reg] * linv[reg]);
    }
  }
}

// ---------------- fused partial-sum + bias + residual + LayerNorm ----------
__global__ __launch_bounds__(256) void ln_kernel(
    const float* __restrict__ xin0, const float* __restrict__ xin1,
    const float* __restrict__ bias, const float* __restrict__ res,
    const float* __restrict__ gam, const float* __restrict__ bet,
    float* __restrict__ outf, u16* __restrict__ outb, int do_relu)
{
  __shared__ float red[4];
  __shared__ float red2[4];
  int row = blockIdx.x, t = threadIdx.x;
  size_t base = (size_t)row * 512;
  float a0 = xin0[base + t] + bias[t];
  float a1 = xin0[base + 256 + t] + bias[256 + t];
  if (xin1) { a0 += xin1[base + t]; a1 += xin1[base + 256 + t]; }
  if (do_relu) { a0 = fmaxf(a0, 0.f); a1 = fmaxf(a1, 0.f); }
  a0 += res[base + t]; a1 += res[base + 256 + t];

  float s = a0 + a1;
  #pragma unroll
  for (int off = 32; off > 0; off >>= 1) s += __shfl_xor(s, off);
  if ((t & 63) == 0) red[t >> 6] = s;
  __syncthreads();
  float mu = (red[0] + red[1] + red[2] + red[3]) * (1.f / 512.f);

  float d0 = a0 - mu, d1 = a1 - mu;
  float q = d0 * d0 + d1 * d1;
  #pragma unroll
  for (int off = 32; off > 0; off >>= 1) q += __shfl_xor(q, off);
  if ((t & 63) == 0) red2[t >> 6] = q;
  __syncthreads();
  float var = (red2[0] + red2[1] + red2[2] + red2[3]) * (1.f / 512.f);
  float rs = rsqrtf(var + 1e-5f);

  float o0 = d0 * rs * gam[t] + bet[t];
  float o1 = d1 * rs * gam[t + 256] + bet[t + 256];
  outf[base + t] = o0;
  outf[base + 256 + t] = o1;
  if (outb) { outb[base + t] = f2bf(o0); outb[base + 256 + t] = f2bf(o1); }
}

// ---------------- host launch ----------------
extern "C" void kernel_launch(void* const* d_in, const int* in_sizes, int n_in,
                              void* d_out, int out_size, void* d_ws, size_t ws_size,
                              hipStream_t stream) {
  const float* x   = (const float*)d_in[0];
  const float* Wq  = (const float*)d_in[1];
  const float* bq  = (const float*)d_in[2];
  const float* Wk  = (const float*)d_in[3];
  const float* bk  = (const float*)d_in[4];  // cancels under softmax
  const float* Wv  = (const float*)d_in[5];
  const float* bv  = (const float*)d_in[6];
  const float* Wo  = (const float*)d_in[7];
  const float* bo  = (const float*)d_in[8];
  const float* g1  = (const float*)d_in[9];
  const float* bn1 = (const float*)d_in[10];
  const float* W1  = (const float*)d_in[11];
  const float* bf1 = (const float*)d_in[12];
  const float* W2  = (const float*)d_in[13];
  const float* bf2 = (const float*)d_in[14];
  const float* g2  = (const float*)d_in[15];
  const float* bn2 = (const float*)d_in[16];
  (void)bk;

  char* ws = (char*)d_ws;
  u16* Krep = (u16*)(ws + 0);            // x bf16 [8][1024][512] (K + GEMM A)
  u16* xb   = Krep;
  u16* Wqb = (u16*)(ws + 67108864);      // dead after Mt GEMM
  u16* WcT  = (u16*)(ws + 67108864);     // (W1.W2)^T [512][512], after Wqb dies
  u16* Wkb = (u16*)(ws + 71303168);      // dead after Mt GEMM
  float* bcp = (float*)(ws + 71303168);  // bc = b1.W2 + b2, after Wkb dies
  u16* Wvb = (u16*)(ws + 75497472);      // Wv bf16 (plain, 4 MB)
  u16* WoT = (u16*)(ws + 79691776);
  u16* W1b = (u16*)(ws + 83886080);      // W1 bf16 plain [512][2048]
  u16* W2T = (u16*)(ws + 85983232);      // W2^T [512][2048]
  u16* Mt  = (u16*)(ws + 88080384);
  float* wbuf = (float*)(ws + 92274688);
  u16* cc  = (u16*)(ws + 92291072);      // 67.1 MB U = P.x  [B][T][H*D]
  u16* Tg  = (u16*)(ws + 159399936);     // 67.1 MB [H][B][1024][512]
  u16* XT  = (u16*)(ws + 226508800);     // 8.4 MB x^T per b [512][1024]
  u16* WvWoT = (u16*)(ws + 234897408);   // 4.2 MB (Wv.Wo)^T [512][4096]
  float* bop = (float*)(ws + 239091712); // 2 KB bo' = bo + sum bv.Wo
  float* y1f  = (float*)(ws + 159399936);
  u16*   y1b  = (u16*)(ws + 176177152);
  float* mha0 = (float*)(ws + 184565760);
  float* mha1 = (float*)(ws + 201342976);
  float* ff20 = (float*)(ws + 125845504); // over cc (dead after Wo GEMM)

  vec_fold<<<32, 256, 0, stream>>>(bv, Wo, bo, bop, 256);      // K=4096
  cvt_all<<<18432, 256, 0, stream>>>(x, Krep, XT, Wq, Wk, Wv, Wo, W1, W2,
                                     Wqb, Wkb, Wvb, WoT, W1b, W2T);
  gemm_bt<128><<<dim3(4, 4, 8), 256, 0, stream>>>(Wkb, Wqb, nullptr, Mt,
      512, 512, 512, 512, 512, 262144LL, 0LL, 0LL, 524288LL, 1);
  wk_bias<<<1024, 256, 0, stream>>>(Wk, bq, wbuf);
  vec_fold<<<32, 256, 0, stream>>>(bf1, W2, bf2, bcp, 128);    // K=2048
  // WvWoT[e][h*512+d] = sum_c Wv_h[d][c] * Wo[h*512+c][e]
  gemm_bt<128><<<dim3(4, 4, 8), 256, 0, stream>>>(WoT, Wvb, nullptr, WvWoT,
      512, 4096, 512, 4096, 512, 512LL, 261632LL, 0LL, 1024LL, 1);
  // WcT[j][k] = sum_t W2T[j][t] * W1b[k][t]  (FFN collapse: Wc = W1.W2)
  gemm_bt<128><<<dim3(4, 4, 1), 256, 0, stream>>>(W2T, W1b, nullptr, WcT,
      512, 512, 2048, 2048, 2048, 0LL, 0LL, 0LL, 0LL, 1);

  gemm_t8<<<dim3(4, 64, 8), 256, 0, stream>>>(xb, Mt, wbuf, Tg);
  attn_kernel<<<dim3(8, 16, 8), 256, 0, stream>>>(Tg, Krep, XT, cc, 0);

  gemm_bt<64><<<dim3(4, 128, 2), 256, 0, stream>>>(cc, WvWoT, nullptr, mha0,
      8192, 512, 2048, 4096, 4096, 2048LL, 0LL, 0LL, 16777216LL, 0);
  ln_kernel<<<8192, 256, 0, stream>>>(mha0, mha1, bop, x, g1, bn1, y1f, y1b, 0);

  // collapsed FFN: ff20 = y1 . Wc  (bias bc added inside ln2, then ReLU+res)
  gemm_bt<128><<<dim3(4, 64, 1), 256, 0, stream>>>(y1b, WcT, nullptr, ff20,
      8192, 512, 512, 512, 512, 0LL, 0LL, 0LL, 0LL, 0);

  ln_kernel<<<8192, 256, 0, stream>>>(ff20, nullptr, bcp, y1f, g2, bn2,
                                      (float*)d_out, nullptr, 1);
}

// Round 12
// 629.710 us; speedup vs baseline: 1.0042x; 1.0042x over previous
//
#include <hip/hip_runtime.h>

using u16 = unsigned short;
using bf16x8 = __attribute__((ext_vector_type(8))) short;
using f32x4 = __attribute__((ext_vector_type(4))) float;
using f32x16 = __attribute__((ext_vector_type(16))) float;

__device__ __forceinline__ u16 f2bf(float f) {
  unsigned x = __float_as_uint(f);
  x += 0x7fffu + ((x >> 16) & 1u);
  return (u16)(x >> 16);
}

__device__ __forceinline__ void gl2lds16(const u16* g, u16* l) {
  __builtin_amdgcn_global_load_lds(
      (const __attribute__((address_space(1))) unsigned int*)g,
      (__attribute__((address_space(3))) unsigned int*)l, 16, 0, 0);
}

// ---------------- consolidated cast + transposes (1 launch) ----------------
__global__ __launch_bounds__(256) void cvt_all(
    const float* __restrict__ x, u16* __restrict__ Krep, u16* __restrict__ XT,
    const float* __restrict__ Wq, const float* __restrict__ Wk,
    const float* __restrict__ Wv, const float* __restrict__ Wo,
    const float* __restrict__ W1, const float* __restrict__ W2,
    u16* __restrict__ Wqb, u16* __restrict__ Wkb, u16* __restrict__ Wvb,
    u16* __restrict__ WoT, u16* __restrict__ W1b, u16* __restrict__ W2T)
{
  int b = blockIdx.x, tid = threadIdx.x;
  if (b < 11264) {
    const float* s; u16* d; int i;
    if (b < 4096)       { s = x;  d = Krep; i = b * 1024 + tid * 4; }
    else if (b < 6144)  { s = Wq; d = Wqb;  i = (b - 4096) * 1024 + tid * 4; }
    else if (b < 8192)  { s = Wk; d = Wkb;  i = (b - 6144) * 1024 + tid * 4; }
    else if (b < 10240) { s = Wv; d = Wvb;  i = (b - 8192) * 1024 + tid * 4; }
    else                { s = W1; d = W1b;  i = (b - 10240) * 1024 + tid * 4; }
    float4 v = *(const float4*)(s + i);
    ushort4 o;
    o.x = f2bf(v.x); o.y = f2bf(v.y); o.z = f2bf(v.z); o.w = f2bf(v.w);
    *(ushort4*)(d + i) = o;
    return;
  }
  __shared__ float T[32][33];
  const float* s; u16* d; int K, N, k0, n0;
  int i = b - 11264;
  if (i < 4096) {
    int b8 = i >> 9, j = i & 511;
    s = x + (size_t)b8 * 524288; d = XT + (size_t)b8 * 524288;
    K = 1024; N = 512; n0 = (j % 16) * 32; k0 = (j / 16) * 32;
  } else if (i < 6144) {
    int j = i - 4096;
    s = Wo; d = WoT; K = 4096; N = 512; n0 = (j % 16) * 32; k0 = (j / 16) * 32;
  } else {
    int j = i - 6144;
    s = W2; d = W2T; K = 2048; N = 512; n0 = (j % 16) * 32; k0 = (j / 16) * 32;
  }
  int r = tid >> 3, c4 = (tid & 7) << 2;
  float4 v = *(const float4*)(s + (size_t)(k0 + r) * N + n0 + c4);
  T[r][c4 + 0] = v.x; T[r][c4 + 1] = v.y; T[r][c4 + 2] = v.z; T[r][c4 + 3] = v.w;
  __syncthreads();
  ushort4 o;
  o.x = f2bf(T[c4 + 0][r]); o.y = f2bf(T[c4 + 1][r]);
  o.z = f2bf(T[c4 + 2][r]); o.w = f2bf(T[c4 + 3][r]);
  *(ushort4*)(d + (size_t)(n0 + r) * K + k0 + c4) = o;
}

// ---------------- w = Wk . bq per head (wave per output row) ---------------
__global__ __launch_bounds__(256) void wk_bias(
    const float* __restrict__ Wk, const float* __restrict__ bq,
    float* __restrict__ wbuf)
{
  int r = blockIdx.x * 4 + (threadIdx.x >> 6);
  int lane = threadIdx.x & 63;
  int h = r >> 9, a = r & 511;
  const float* row = Wk + ((size_t)h * 512 + a) * 512 + lane * 8;
  const float* bqp = bq + h * 512 + lane * 8;
  float4 w0 = *(const float4*)row, w1 = *(const float4*)(row + 4);
  float4 b0 = *(const float4*)bqp, b1 = *(const float4*)(bqp + 4);
  float s = w0.x * b0.x + w0.y * b0.y + w0.z * b0.z + w0.w * b0.w +
            w1.x * b1.x + w1.y * b1.y + w1.z * b1.z + w1.w * b1.w;
  #pragma unroll
  for (int off = 1; off < 64; off <<= 1) s += __shfl_xor(s, off);
  if (lane == 0) wbuf[r] = s;
}

// ---------- out[e] = c[e] + sum_k v[k]*W[k*512+e], K = kc*16 ---------------
__global__ __launch_bounds__(256) void vec_fold(
    const float* __restrict__ v, const float* __restrict__ W,
    const float* __restrict__ c, float* __restrict__ out, int kc)
{
  __shared__ float part[16][17];
  int ei = threadIdx.x & 15, ch = threadIdx.x >> 4;
  int e = blockIdx.x * 16 + ei;
  float s = 0.f;
  for (int k = ch * kc; k < ch * kc + kc; k++)
    s += v[k] * W[(size_t)k * 512 + e];
  part[ei][ch] = s;
  __syncthreads();
  if (threadIdx.x < 16) {
    float t = c[blockIdx.x * 16 + threadIdx.x];
    #pragma unroll
    for (int cc = 0; cc < 16; cc++) t += part[threadIdx.x][cc];
    out[blockIdx.x * 16 + threadIdx.x] = t;
  }
}

// --------- WcT = sum of 16 split-K partial slabs, cast to bf16 -------------
__global__ __launch_bounds__(256) void reduce_cast(
    const float* __restrict__ part, u16* __restrict__ out)
{
  int i = (blockIdx.x * 256 + threadIdx.x) * 4;
  float4 s = *(const float4*)(part + i);
  #pragma unroll
  for (int z = 1; z < 16; z++) {
    float4 v = *(const float4*)(part + (size_t)z * 262144 + i);
    s.x += v.x; s.y += v.y; s.z += v.z; s.w += v.w;
  }
  ushort4 o;
  o.x = f2bf(s.x); o.y = f2bf(s.y); o.z = f2bf(s.z); o.w = f2bf(s.w);
  *(ushort4*)(out + i) = o;
}

// ---------------- generic bf16 GEMM, 2-phase double-buffered ----------------
template<int BM>
__global__ __launch_bounds__(256) void gemm_bt(
    const u16* __restrict__ A, const u16* __restrict__ Bt,
    const float* __restrict__ bias, void* __restrict__ Cout,
    int M, int N, int K, int lda, int ldb, long long kzoff,
    long long sBz, long long sbz, long long sCzBytes, int out_mode)
{
  constexpr int MT = BM / 32;
  constexpr int TILE = BM * 32 + 128 * 32;     // u16 per buffer
  __shared__ __align__(16) u16 smem[2 * TILE];
  const f32x4 zero4 = {0.f, 0.f, 0.f, 0.f};

  const u16* Ap = A + (size_t)blockIdx.z * (size_t)kzoff;
  const u16* Bp = Bt + (size_t)blockIdx.z * (size_t)(sBz + kzoff);
  const float* biasp = bias ? bias + (size_t)blockIdx.z * sbz : nullptr;
  char* Cp = (char*)Cout + (size_t)blockIdx.z * sCzBytes;

  // XCD-chunk swizzle of the (x,y) plane (T1; P % 8 == 0 for all grids)
  int P = gridDim.x * gridDim.y;
  int p = blockIdx.x + gridDim.x * blockIdx.y;
  int f = (p & 7) * (P >> 3) + (p >> 3);
  int bx = f % gridDim.x, by = f / gridDim.x;

  int tid = threadIdx.x;
  int lane = tid & 63, wave = tid >> 6;
  int m = lane & 15, quad = lane >> 4;
  int wm = (wave >> 1) * (BM / 2), wn = (wave & 1) * 64;
  int m0 = by * BM, n0 = bx * 128;
  int lr = lane >> 2, lc = (lane & 3) << 3;

  auto stage = [&](int buf, int k0) {
    u16* As = smem + buf * TILE;
    u16* Bs = As + BM * 32;
    #pragma unroll
    for (int i = 0; i < BM / 64; i++) {
      int rb = i * 64 + wave * 16;
      gl2lds16(Ap + (size_t)(m0 + rb + lr) * lda + k0 + lc, &As[rb * 32]);
    }
    #pragma unroll
    for (int i = 0; i < 2; i++) {
      int rb = i * 64 + wave * 16;
      gl2lds16(Bp + (size_t)(n0 + rb + lr) * ldb + k0 + lc, &Bs[rb * 32]);
    }
  };

  f32x4 acc[MT][4];
  #pragma unroll
  for (int i = 0; i < MT; i++)
    #pragma unroll
    for (int j = 0; j < 4; j++) acc[i][j] = zero4;

  stage(0, 0);
  asm volatile("s_waitcnt vmcnt(0)" ::: "memory");
  __builtin_amdgcn_s_barrier();

  int nt = K >> 5;
  int cur = 0;
  for (int t = 0; t < nt; t++) {
    if (t + 1 < nt) stage(cur ^ 1, (t + 1) << 5);   // DMA flies under MFMAs

    u16* As = smem + cur * TILE;
    u16* Bs = As + BM * 32;
    bf16x8 af[MT], bfr[4];
    #pragma unroll
    for (int tt = 0; tt < MT; tt++)
      af[tt] = *(const bf16x8*)&As[(wm + tt * 16 + m) * 32 + quad * 8];
    #pragma unroll
    for (int tt = 0; tt < 4; tt++)
      bfr[tt] = *(const bf16x8*)&Bs[(wn + tt * 16 + m) * 32 + quad * 8];
    #pragma unroll
    for (int mt = 0; mt < MT; mt++)
      #pragma unroll
      for (int nt2 = 0; nt2 < 4; nt2++)
        acc[mt][nt2] = __builtin_amdgcn_mfma_f32_16x16x32_bf16(af[mt], bfr[nt2],
                                                               acc[mt][nt2], 0, 0, 0);
    asm volatile("s_waitcnt vmcnt(0)" ::: "memory");
    __builtin_amdgcn_s_barrier();
    cur ^= 1;
  }

  if (out_mode == 2) {
    u16* Ts = smem;
    int b2 = m0 >> 10, t20 = m0 & 1023;
    int half = wave >> 1;
    #pragma unroll
    for (int mt = 0; mt < MT; mt++) {
      #pragma unroll
      for (int nt2 = 0; nt2 < 4; nt2++) {
        int colc = wn + nt2 * 16 + m;
        float bb = biasp ? biasp[n0 + colc] : 0.f;
        #pragma unroll
        for (int r = 0; r < 4; r++)
          Ts[colc * 40 + half * 16 + quad * 4 + r] = f2bf(acc[mt][nt2][r] + bb);
      }
      __syncthreads();
      #pragma unroll
      for (int it = 0; it < 2; it++) {
        int c = (tid >> 2) + 64 * it;
        int j = tid & 3;
        bf16x8 v = *(const bf16x8*)&Ts[c * 40 + j * 8];
        int tg = t20 + (j >> 1) * (BM / 2) + mt * 16 + (j & 1) * 8;
        *(bf16x8*)((u16*)Cp + ((size_t)b2 * 512 + n0 + c) * 1024 + tg) = v;
      }
      __syncthreads();
    }
    return;
  }

  #pragma unroll
  for (int nt2 = 0; nt2 < 4; nt2++) {
    int col = n0 + wn + nt2 * 16 + m;
    float bb = biasp ? biasp[col] : 0.f;
    #pragma unroll
    for (int mt = 0; mt < MT; mt++) {
      #pragma unroll
      for (int r = 0; r < 4; r++) {
        int row = m0 + wm + mt * 16 + quad * 4 + r;
        float v = acc[mt][nt2][r] + bb;
        if (out_mode == 1) {
          ((u16*)Cp)[(size_t)row * N + col] = f2bf(v);
        } else {
          ((float*)Cp)[(size_t)row * N + col] = v;
        }
      }
    }
  }
}

// ---------------- T projection only (2-phase double-buffered) ---------------
__global__ __launch_bounds__(256) void gemm_t8(
    const u16* __restrict__ A, const u16* __restrict__ Mt,
    const float* __restrict__ wbuf, u16* __restrict__ Tg)
{
  constexpr int TILE = 8192;
  __shared__ __align__(16) u16 smem[2 * TILE];
  const f32x4 zero4 = {0.f, 0.f, 0.f, 0.f};

  int h = blockIdx.z;
  const u16* Bp = Mt + (size_t)h * 262144;
  const float* biasp = wbuf + h * 512;
  u16* Og = Tg + (size_t)h * 4194304;

  int P = gridDim.x * gridDim.y;
  int p = blockIdx.x + gridDim.x * blockIdx.y;
  int f = (p & 7) * (P >> 3) + (p >> 3);
  int bx = f % gridDim.x, by = f / gridDim.x;

  int tid = threadIdx.x;
  int lane = tid & 63, wave = tid >> 6;
  int m = lane & 15, quad = lane >> 4;
  int wm = (wave >> 1) * 64, wn = (wave & 1) * 64;
  int m0 = by * 128, n0 = bx * 128;
  int lr = lane >> 2, lc = (lane & 3) << 3;

  auto stage = [&](int buf, int k0) {
    u16* As = smem + buf * TILE;
    u16* Bs = As + 4096;
    #pragma unroll
    for (int i = 0; i < 2; i++) {
      int rb = i * 64 + wave * 16;
      gl2lds16(A + (size_t)(m0 + rb + lr) * 512 + k0 + lc, &As[rb * 32]);
      gl2lds16(Bp + (size_t)(n0 + rb + lr) * 512 + k0 + lc, &Bs[rb * 32]);
    }
  };

  f32x4 acc[4][4];
  #pragma unroll
  for (int i = 0; i < 4; i++)
    #pragma unroll
    for (int j = 0; j < 4; j++) acc[i][j] = zero4;

  stage(0, 0);
  asm volatile("s_waitcnt vmcnt(0)" ::: "memory");
  __builtin_amdgcn_s_barrier();

  int cur = 0;
  for (int t = 0; t < 16; t++) {
    if (t + 1 < 16) stage(cur ^ 1, (t + 1) << 5);

    u16* As = smem + cur * TILE;
    u16* Bs = As + 4096;
    bf16x8 af[4], bfr[4];
    #pragma unroll
    for (int tt = 0; tt < 4; tt++) {
      af[tt]  = *(const bf16x8*)&As[(wm + tt * 16 + m) * 32 + quad * 8];
      bfr[tt] = *(const bf16x8*)&Bs[(wn + tt * 16 + m) * 32 + quad * 8];
    }
    #pragma unroll
    for (int mt = 0; mt < 4; mt++)
      #pragma unroll
      for (int nt = 0; nt < 4; nt++)
        acc[mt][nt] = __builtin_amdgcn_mfma_f32_16x16x32_bf16(af[mt], bfr[nt],
                                                              acc[mt][nt], 0, 0, 0);
    asm volatile("s_waitcnt vmcnt(0)" ::: "memory");
    __builtin_amdgcn_s_barrier();
    cur ^= 1;
  }

  #pragma unroll
  for (int nt = 0; nt < 4; nt++) {
    int col = n0 + wn + nt * 16 + m;
    float bb = biasp[col];
    #pragma unroll
    for (int mt = 0; mt < 4; mt++) {
      #pragma unroll
      for (int r = 0; r < 4; r++) {
        int row = m0 + wm + mt * 16 + quad * 4 + r;
        Og[(size_t)row * 512 + col] = f2bf(acc[mt][nt][r] + bb);
      }
    }
  }
}

// ---------------- flash attention (R9-proven, unchanged) --------------------
__global__ __launch_bounds__(256, 2) void attn_kernel(
    const u16* __restrict__ Tg, const u16* __restrict__ Krep,
    const u16* __restrict__ XT, u16* __restrict__ Oc, int h0)
{
  __shared__ __align__(16) u16 Kt[32][520];   // 33,280 B
  __shared__ __align__(16) u16 Vt[512 * 32];  // 32,768 B (chunk-XOR swizzled)
  __shared__ __align__(16) u16 Pl[64][40];    //  5,120 B
  __shared__ float lred[64];
  const f32x4 zero4 = {0.f, 0.f, 0.f, 0.f};
  const f32x16 zero16 = {0.f,0.f,0.f,0.f,0.f,0.f,0.f,0.f,
                         0.f,0.f,0.f,0.f,0.f,0.f,0.f,0.f};

  int b = blockIdx.x, qb = blockIdx.y, z = blockIdx.z;
  int h = h0 + z;

  size_t hb = ((size_t)z * 8 + b) * (size_t)(1024 * 512);
  const u16* Tp = Tg + hb;
  const u16* Kp = Krep + (size_t)b * (size_t)(1024 * 512); // x slab (K)
  const u16* Vp = XT + (size_t)b * (size_t)(512 * 1024);   // x^T slab ("V")

  int tid = threadIdx.x, lane = tid & 63, wave = tid >> 6;
  int m = lane & 15, quad = lane >> 4;         // QK roles (16x16)
  int l31 = lane & 31, hi = lane >> 5;         // PV roles (32x32)
  int qh = wave >> 1, dh = wave & 1;
  int q0 = qb * 64 + wave * 16;

  int vr = lane >> 2;
  int vc = (((lane & 3) ^ ((lane >> 3) & 3)) << 3);
  int vswz = (l31 >> 1) & 3;

  bf16x8 aq[16];
  #pragma unroll
  for (int kc = 0; kc < 16; kc++)
    aq[kc] = *(const bf16x8*)(Tp + (size_t)(q0 + m) * 512 + kc * 32 + quad * 8);

  f32x16 o[8];
  #pragma unroll
  for (int dt = 0; dt < 8; dt++) o[dt] = zero16;
  float lsum_acc[4] = {0.f, 0.f, 0.f, 0.f};
  const float scale = 0.04419417382415922f;

  // prologue: stage tile 0
  #pragma unroll
  for (int r = 0; r < 8; r++) {
    int row = wave * 8 + r;
    gl2lds16(Kp + (size_t)row * 512 + lane * 8, &Kt[row][0]);
  }
  #pragma unroll
  for (int j = 0; j < 8; j++) {
    int rb = wave * 128 + j * 16;
    gl2lds16(Vp + (size_t)(rb + vr) * 1024 + vc, &Vt[rb * 32]);
  }

  for (int kt = 0; kt < 32; kt++) {
    // ---- BAR-A: K(kt) complete everywhere ----
    asm volatile("s_waitcnt vmcnt(8)" ::: "memory");
    __builtin_amdgcn_sched_barrier(0);
    __builtin_amdgcn_s_barrier();
    __builtin_amdgcn_sched_barrier(0);

    // ---- QK ----
    f32x4 s0 = zero4, s1 = zero4;
    #pragma unroll
    for (int kc = 0; kc < 16; kc++) {
      bf16x8 bk0 = *(const bf16x8*)&Kt[m][kc * 32 + quad * 8];
      bf16x8 bk1 = *(const bf16x8*)&Kt[m + 16][kc * 32 + quad * 8];
      s0 = __builtin_amdgcn_mfma_f32_16x16x32_bf16(aq[kc], bk0, s0, 0, 0, 0);
      s1 = __builtin_amdgcn_mfma_f32_16x16x32_bf16(aq[kc], bk1, s1, 0, 0, 0);
    }

    // ---- exp, P write, per-lane lsum partial ----
    #pragma unroll
    for (int r = 0; r < 4; r++) {
      float e0 = __expf(s0[r] * scale);
      float e1 = __expf(s1[r] * scale);
      u16 p0 = f2bf(e0), p1 = f2bf(e1);
      int prow = wave * 16 + quad * 4 + r;
      Pl[prow][m] = p0;
      Pl[prow][m + 16] = p1;
      lsum_acc[r] += __uint_as_float((unsigned)p0 << 16) +
                     __uint_as_float((unsigned)p1 << 16);
    }

    // ---- BAR-B: V(kt) ready + P visible + Kt free ----
    asm volatile("s_waitcnt vmcnt(0) lgkmcnt(0)" ::: "memory");
    __builtin_amdgcn_sched_barrier(0);
    __builtin_amdgcn_s_barrier();
    __builtin_amdgcn_sched_barrier(0);

    if (kt < 31) {                 // K(kt+1) DMA flies under PV
      int kr1 = (kt + 1) * 32;
      #pragma unroll
      for (int r = 0; r < 8; r++) {
        int row = wave * 8 + r;
        gl2lds16(Kp + (size_t)(kr1 + row) * 512 + lane * 8, &Kt[row][0]);
      }
    }

    // ---- PV: 32x32x16 ----
    const u16* PlRow = &Pl[qh * 32 + l31][0];
    #pragma unroll
    for (int ks = 0; ks < 2; ks++) {
      bf16x8 pa = *(const bf16x8*)(PlRow + ks * 16 + hi * 8);
      #pragma unroll
      for (int dt = 0; dt < 8; dt++) {
        int rr = dh * 256 + dt * 32 + l31;
        int cc2 = (((ks * 2 + hi) ^ vswz) << 3);
        bf16x8 bv = *(const bf16x8*)&Vt[rr * 32 + cc2];
        o[dt] = __builtin_amdgcn_mfma_f32_32x32x16_bf16(pa, bv, o[dt], 0, 0, 0);
      }
    }

    // ---- BAR-C: PV reads delivered; Vt, Pl free ----
    asm volatile("s_waitcnt lgkmcnt(0)" ::: "memory");
    __builtin_amdgcn_sched_barrier(0);
    __builtin_amdgcn_s_barrier();
    __builtin_amdgcn_sched_barrier(0);

    if (kt < 31) {                 // V(kt+1) DMA flies under next QK
      int kr1 = (kt + 1) * 32;
      #pragma unroll
      for (int j = 0; j < 8; j++) {
        int rb = wave * 128 + j * 16;
        gl2lds16(Vp + (size_t)(rb + vr) * 1024 + kr1 + vc, &Vt[rb * 32]);
      }
    }
  }

  // ---- deferred lsum reduce (once, not per-kt) ----
  #pragma unroll
  for (int r = 0; r < 4; r++) {
    float t = lsum_acc[r];
    t += __shfl_xor(t, 1); t += __shfl_xor(t, 2);
    t += __shfl_xor(t, 4); t += __shfl_xor(t, 8);
    lsum_acc[r] = t;
  }
  if (m == 0) {
    #pragma unroll
    for (int r = 0; r < 4; r++)
      lred[wave * 16 + quad * 4 + r] = lsum_acc[r];
  }
  __syncthreads();

  float linv[16];
  #pragma unroll
  for (int g = 0; g < 4; g++) {
    float4 t = *(const float4*)&lred[qh * 32 + 8 * g + 4 * hi];
    linv[4 * g + 0] = 1.f / t.x; linv[4 * g + 1] = 1.f / t.y;
    linv[4 * g + 2] = 1.f / t.z; linv[4 * g + 3] = 1.f / t.w;
  }

  size_t obase = (size_t)b * 1024 + qb * 64 + qh * 32;
  #pragma unroll
  for (int dt = 0; dt < 8; dt++) {
    int dcol = dh * 256 + dt * 32 + l31;
    #pragma unroll
    for (int reg = 0; reg < 16; reg++) {
      int rowq = (reg & 3) + 8 * (reg >> 2) + 4 * hi;
      Oc[((obase + rowq) * 8 + h) * 512 + dcol] = f2bf(o[dt][reg] * linv[reg]);
    }
  }
}

// ---------------- fused partial-sum + bias + residual + LayerNorm ----------
__global__ __launch_bounds__(256) void ln_kernel(
    const float* __restrict__ xin0, const float* __restrict__ xin1,
    const float* __restrict__ bias, const float* __restrict__ res,
    const float* __restrict__ gam, const float* __restrict__ bet,
    float* __restrict__ outf, u16* __restrict__ outb, int do_relu)
{
  __shared__ float red[4];
  __shared__ float red2[4];
  int row = blockIdx.x, t = threadIdx.x;
  size_t base = (size_t)row * 512;
  float a0 = xin0[base + t] + bias[t];
  float a1 = xin0[base + 256 + t] + bias[256 + t];
  if (xin1) { a0 += xin1[base + t]; a1 += xin1[base + 256 + t]; }
  if (do_relu) { a0 = fmaxf(a0, 0.f); a1 = fmaxf(a1, 0.f); }
  a0 += res[base + t]; a1 += res[base + 256 + t];

  float s = a0 + a1;
  #pragma unroll
  for (int off = 32; off > 0; off >>= 1) s += __shfl_xor(s, off);
  if ((t & 63) == 0) red[t >> 6] = s;
  __syncthreads();
  float mu = (red[0] + red[1] + red[2] + red[3]) * (1.f / 512.f);

  float d0 = a0 - mu, d1 = a1 - mu;
  float q = d0 * d0 + d1 * d1;
  #pragma unroll
  for (int off = 32; off > 0; off >>= 1) q += __shfl_xor(q, off);
  if ((t & 63) == 0) red2[t >> 6] = q;
  __syncthreads();
  float var = (red2[0] + red2[1] + red2[2] + red2[3]) * (1.f / 512.f);
  float rs = rsqrtf(var + 1e-5f);

  float o0 = d0 * rs * gam[t] + bet[t];
  float o1 = d1 * rs * gam[t + 256] + bet[t + 256];
  outf[base + t] = o0;
  outf[base + 256 + t] = o1;
  if (outb) { outb[base + t] = f2bf(o0); outb[base + 256 + t] = f2bf(o1); }
}

// ---------------- host launch ----------------
extern "C" void kernel_launch(void* const* d_in, const int* in_sizes, int n_in,
                              void* d_out, int out_size, void* d_ws, size_t ws_size,
                              hipStream_t stream) {
  const float* x   = (const float*)d_in[0];
  const float* Wq  = (const float*)d_in[1];
  const float* bq  = (const float*)d_in[2];
  const float* Wk  = (const float*)d_in[3];
  const float* bk  = (const float*)d_in[4];  // cancels under softmax
  const float* Wv  = (const float*)d_in[5];
  const float* bv  = (const float*)d_in[6];
  const float* Wo  = (const float*)d_in[7];
  const float* bo  = (const float*)d_in[8];
  const float* g1  = (const float*)d_in[9];
  const float* bn1 = (const float*)d_in[10];
  const float* W1  = (const float*)d_in[11];
  const float* bf1 = (const float*)d_in[12];
  const float* W2  = (const float*)d_in[13];
  const float* bf2 = (const float*)d_in[14];
  const float* g2  = (const float*)d_in[15];
  const float* bn2 = (const float*)d_in[16];
  (void)bk;

  char* ws = (char*)d_ws;
  u16* Krep = (u16*)(ws + 0);            // x bf16 [8][1024][512] (K + GEMM A)
  u16* xb   = Krep;
  u16* Wqb = (u16*)(ws + 67108864);      // dead after Mt GEMM
  u16* WcT  = (u16*)(ws + 67108864);     // (W1.W2)^T [512][512], after Wqb dies
  u16* Wkb = (u16*)(ws + 71303168);      // dead after Mt GEMM
  float* bcp = (float*)(ws + 71303168);  // bc = b1.W2 + b2, after Wkb dies
  u16* Wvb = (u16*)(ws + 75497472);      // Wv bf16 (plain, 4 MB)
  u16* WoT = (u16*)(ws + 79691776);
  u16* W1b = (u16*)(ws + 83886080);      // W1 bf16 plain [512][2048]
  u16* W2T = (u16*)(ws + 85983232);      // W2^T [512][2048]
  u16* Mt  = (u16*)(ws + 88080384);
  float* wbuf = (float*)(ws + 92274688);
  u16* cc  = (u16*)(ws + 92291072);      // 67.1 MB U = P.x  [B][T][H*D]
  float* WcP = (float*)(ws + 92291072);  // 16 MB split-K partials (pre-attn)
  u16* Tg  = (u16*)(ws + 159399936);     // 67.1 MB [H][B][1024][512]
  u16* XT  = (u16*)(ws + 226508800);     // 8.4 MB x^T per b [512][1024]
  u16* WvWoT = (u16*)(ws + 234897408);   // 4.2 MB (Wv.Wo)^T [512][4096]
  float* bop = (float*)(ws + 239091712); // 2 KB bo' = bo + sum bv.Wo
  float* y1f  = (float*)(ws + 159399936);
  u16*   y1b  = (u16*)(ws + 176177152);
  float* mha0 = (float*)(ws + 184565760);
  float* mha1 = (float*)(ws + 201342976);
  float* ff20 = (float*)(ws + 125845504); // over cc (dead after Wo GEMM)

  vec_fold<<<32, 256, 0, stream>>>(bv, Wo, bo, bop, 256);      // K=4096
  cvt_all<<<18432, 256, 0, stream>>>(x, Krep, XT, Wq, Wk, Wv, Wo, W1, W2,
                                     Wqb, Wkb, Wvb, WoT, W1b, W2T);
  gemm_bt<128><<<dim3(4, 4, 8), 256, 0, stream>>>(Wkb, Wqb, nullptr, Mt,
      512, 512, 512, 512, 512, 262144LL, 0LL, 0LL, 524288LL, 1);
  wk_bias<<<1024, 256, 0, stream>>>(Wk, bq, wbuf);
  vec_fold<<<32, 256, 0, stream>>>(bf1, W2, bf2, bcp, 128);    // K=2048
  // WvWoT[e][h*512+d] = sum_c Wv_h[d][c] * Wo[h*512+c][e]
  gemm_bt<128><<<dim3(4, 4, 8), 256, 0, stream>>>(WoT, Wvb, nullptr, WvWoT,
      512, 4096, 512, 4096, 512, 512LL, 261632LL, 0LL, 1024LL, 1);
  // WcT split-K16: partials WcP[z][512][512] f32, then reduce+cast
  gemm_bt<128><<<dim3(4, 4, 16), 256, 0, stream>>>(W2T, W1b, nullptr, WcP,
      512, 512, 128, 2048, 2048, 128LL, 0LL, 0LL, 1048576LL, 0);
  reduce_cast<<<256, 256, 0, stream>>>(WcP, WcT);

  gemm_t8<<<dim3(4, 64, 8), 256, 0, stream>>>(xb, Mt, wbuf, Tg);
  attn_kernel<<<dim3(8, 16, 8), 256, 0, stream>>>(Tg, Krep, XT, cc, 0);

  gemm_bt<64><<<dim3(4, 128, 2), 256, 0, stream>>>(cc, WvWoT, nullptr, mha0,
      8192, 512, 2048, 4096, 4096, 2048LL, 0LL, 0LL, 16777216LL, 0);
  ln_kernel<<<8192, 256, 0, stream>>>(mha0, mha1, bop, x, g1, bn1, y1f, y1b, 0);

  // collapsed FFN: ff20 = y1 . Wc  (bias bc added inside ln2, then ReLU+res)
  gemm_bt<64><<<dim3(4, 128, 1), 256, 0, stream>>>(y1b, WcT, nullptr, ff20,
      8192, 512, 512, 512, 512, 0LL, 0LL, 0LL, 0LL, 0);

  ln_kernel<<<8192, 256, 0, stream>>>(ff20, nullptr, bcp, y1f, g2, bn2,
                                      (float*)d_out, nullptr, 1);
}

// Round 13
// 536.934 us; speedup vs baseline: 1.1777x; 1.1728x over previous
//
#include <hip/hip_runtime.h>

using u16 = unsigned short;
using bf16x8 = __attribute__((ext_vector_type(8))) short;
using f32x4 = __attribute__((ext_vector_type(4))) float;
using f32x16 = __attribute__((ext_vector_type(16))) float;

__device__ __forceinline__ u16 f2bf(float f) {
  unsigned x = __float_as_uint(f);
  x += 0x7fffu + ((x >> 16) & 1u);
  return (u16)(x >> 16);
}

__device__ __forceinline__ void gl2lds16(const u16* g, u16* l) {
  __builtin_amdgcn_global_load_lds(
      (const __attribute__((address_space(1))) unsigned int*)g,
      (__attribute__((address_space(3))) unsigned int*)l, 16, 0, 0);
}

// ---------------- consolidated cast + transposes (1 launch) ----------------
__global__ __launch_bounds__(256) void cvt_all(
    const float* __restrict__ x, u16* __restrict__ Krep, u16* __restrict__ XT,
    const float* __restrict__ Wq, const float* __restrict__ Wk,
    const float* __restrict__ Wv, const float* __restrict__ Wo,
    const float* __restrict__ W1, const float* __restrict__ W2,
    u16* __restrict__ Wqb, u16* __restrict__ Wkb, u16* __restrict__ Wvb,
    u16* __restrict__ WoT, u16* __restrict__ W1T, u16* __restrict__ W2T)
{
  int b = blockIdx.x, tid = threadIdx.x;
  if (b < 10240) {
    const float* s; u16* d; int i;
    if (b < 4096)      { s = x;  d = Krep; i = b * 1024 + tid * 4; }
    else if (b < 6144) { s = Wq; d = Wqb;  i = (b - 4096) * 1024 + tid * 4; }
    else if (b < 8192) { s = Wk; d = Wkb;  i = (b - 6144) * 1024 + tid * 4; }
    else               { s = Wv; d = Wvb;  i = (b - 8192) * 1024 + tid * 4; }
    float4 v = *(const float4*)(s + i);
    ushort4 o;
    o.x = f2bf(v.x); o.y = f2bf(v.y); o.z = f2bf(v.z); o.w = f2bf(v.w);
    *(ushort4*)(d + i) = o;
    return;
  }
  __shared__ float T[32][33];
  const float* s; u16* d; int K, N, k0, n0;
  int i = b - 10240;
  if (i < 4096) {
    int b8 = i >> 9, j = i & 511;
    s = x + (size_t)b8 * 524288; d = XT + (size_t)b8 * 524288;
    K = 1024; N = 512; n0 = (j % 16) * 32; k0 = (j / 16) * 32;
  } else if (i < 6144) {
    int j = i - 4096;
    s = Wo; d = WoT; K = 4096; N = 512; n0 = (j % 16) * 32; k0 = (j / 16) * 32;
  } else if (i < 7168) {
    int j = i - 6144;
    s = W1; d = W1T; K = 512; N = 2048; n0 = (j % 64) * 32; k0 = (j / 64) * 32;
  } else {
    int j = i - 7168;
    s = W2; d = W2T; K = 2048; N = 512; n0 = (j % 16) * 32; k0 = (j / 16) * 32;
  }
  int r = tid >> 3, c4 = (tid & 7) << 2;
  float4 v = *(const float4*)(s + (size_t)(k0 + r) * N + n0 + c4);
  T[r][c4 + 0] = v.x; T[r][c4 + 1] = v.y; T[r][c4 + 2] = v.z; T[r][c4 + 3] = v.w;
  __syncthreads();
  ushort4 o;
  o.x = f2bf(T[c4 + 0][r]); o.y = f2bf(T[c4 + 1][r]);
  o.z = f2bf(T[c4 + 2][r]); o.w = f2bf(T[c4 + 3][r]);
  *(ushort4*)(d + (size_t)(n0 + r) * K + k0 + c4) = o;
}

// ---------------- w = Wk . bq per head (wave per output row) ---------------
__global__ __launch_bounds__(256) void wk_bias(
    const float* __restrict__ Wk, const float* __restrict__ bq,
    float* __restrict__ wbuf)
{
  int r = blockIdx.x * 4 + (threadIdx.x >> 6);
  int lane = threadIdx.x & 63;
  int h = r >> 9, a = r & 511;
  const float* row = Wk + ((size_t)h * 512 + a) * 512 + lane * 8;
  const float* bqp = bq + h * 512 + lane * 8;
  float4 w0 = *(const float4*)row, w1 = *(const float4*)(row + 4);
  float4 b0 = *(const float4*)bqp, b1 = *(const float4*)(bqp + 4);
  float s = w0.x * b0.x + w0.y * b0.y + w0.z * b0.z + w0.w * b0.w +
            w1.x * b1.x + w1.y * b1.y + w1.z * b1.z + w1.w * b1.w;
  #pragma unroll
  for (int off = 1; off < 64; off <<= 1) s += __shfl_xor(s, off);
  if (lane == 0) wbuf[r] = s;
}

// ---------------- bo' = bo + sum_h bv_h . Wo_h (rank-1 fold of bv) ---------
__global__ __launch_bounds__(256) void bo_fold(
    const float* __restrict__ bv, const float* __restrict__ Wo,
    const float* __restrict__ bo, float* __restrict__ bop)
{
  __shared__ float part[16][17];
  int ei = threadIdx.x & 15, ch = threadIdx.x >> 4;
  int e = blockIdx.x * 16 + ei;
  float s = 0.f;
  for (int k = ch * 256; k < ch * 256 + 256; k++)
    s += bv[k] * Wo[(size_t)k * 512 + e];
  part[ei][ch] = s;
  __syncthreads();
  if (threadIdx.x < 16) {
    float t = bo[blockIdx.x * 16 + threadIdx.x];
    #pragma unroll
    for (int c = 0; c < 16; c++) t += part[threadIdx.x][c];
    bop[blockIdx.x * 16 + threadIdx.x] = t;
  }
}

// ---------------- generic bf16 GEMM, 2-phase double-buffered ----------------
template<int BM>
__global__ __launch_bounds__(256) void gemm_bt(
    const u16* __restrict__ A, const u16* __restrict__ Bt,
    const float* __restrict__ bias, void* __restrict__ Cout,
    int M, int N, int K, int lda, int ldb, long long kzoff,
    long long sBz, long long sbz, long long sCzBytes, int out_mode)
{
  constexpr int MT = BM / 32;
  constexpr int TILE = BM * 32 + 128 * 32;     // u16 per buffer
  __shared__ __align__(16) u16 smem[2 * TILE];
  const f32x4 zero4 = {0.f, 0.f, 0.f, 0.f};

  const u16* Ap = A + (size_t)blockIdx.z * (size_t)kzoff;
  const u16* Bp = Bt + (size_t)blockIdx.z * (size_t)(sBz + kzoff);
  const float* biasp = bias ? bias + (size_t)blockIdx.z * sbz : nullptr;
  char* Cp = (char*)Cout + (size_t)blockIdx.z * sCzBytes;

  // XCD-chunk swizzle of the (x,y) plane (T1; P % 8 == 0 for all grids)
  int P = gridDim.x * gridDim.y;
  int p = blockIdx.x + gridDim.x * blockIdx.y;
  int f = (p & 7) * (P >> 3) + (p >> 3);
  int bx = f % gridDim.x, by = f / gridDim.x;

  int tid = threadIdx.x;
  int lane = tid & 63, wave = tid >> 6;
  int m = lane & 15, quad = lane >> 4;
  int wm = (wave >> 1) * (BM / 2), wn = (wave & 1) * 64;
  int m0 = by * BM, n0 = bx * 128;
  int lr = lane >> 2, lc = (lane & 3) << 3;

  auto stage = [&](int buf, int k0) {
    u16* As = smem + buf * TILE;
    u16* Bs = As + BM * 32;
    #pragma unroll
    for (int i = 0; i < BM / 64; i++) {
      int rb = i * 64 + wave * 16;
      gl2lds16(Ap + (size_t)(m0 + rb + lr) * lda + k0 + lc, &As[rb * 32]);
    }
    #pragma unroll
    for (int i = 0; i < 2; i++) {
      int rb = i * 64 + wave * 16;
      gl2lds16(Bp + (size_t)(n0 + rb + lr) * ldb + k0 + lc, &Bs[rb * 32]);
    }
  };

  f32x4 acc[MT][4];
  #pragma unroll
  for (int i = 0; i < MT; i++)
    #pragma unroll
    for (int j = 0; j < 4; j++) acc[i][j] = zero4;

  stage(0, 0);
  asm volatile("s_waitcnt vmcnt(0)" ::: "memory");
  __builtin_amdgcn_s_barrier();

  int nt = K >> 5;
  int cur = 0;
  for (int t = 0; t < nt; t++) {
    if (t + 1 < nt) stage(cur ^ 1, (t + 1) << 5);   // DMA flies under MFMAs

    u16* As = smem + cur * TILE;
    u16* Bs = As + BM * 32;
    bf16x8 af[MT], bfr[4];
    #pragma unroll
    for (int tt = 0; tt < MT; tt++)
      af[tt] = *(const bf16x8*)&As[(wm + tt * 16 + m) * 32 + quad * 8];
    #pragma unroll
    for (int tt = 0; tt < 4; tt++)
      bfr[tt] = *(const bf16x8*)&Bs[(wn + tt * 16 + m) * 32 + quad * 8];
    #pragma unroll
    for (int mt = 0; mt < MT; mt++)
      #pragma unroll
      for (int nt2 = 0; nt2 < 4; nt2++)
        acc[mt][nt2] = __builtin_amdgcn_mfma_f32_16x16x32_bf16(af[mt], bfr[nt2],
                                                               acc[mt][nt2], 0, 0, 0);
    asm volatile("s_waitcnt vmcnt(0)" ::: "memory");
    __builtin_amdgcn_s_barrier();
    cur ^= 1;
  }

  if (out_mode == 2) {
    u16* Ts = smem;
    int b2 = m0 >> 10, t20 = m0 & 1023;
    int half = wave >> 1;
    #pragma unroll
    for (int mt = 0; mt < MT; mt++) {
      #pragma unroll
      for (int nt2 = 0; nt2 < 4; nt2++) {
        int colc = wn + nt2 * 16 + m;
        float bb = biasp ? biasp[n0 + colc] : 0.f;
        #pragma unroll
        for (int r = 0; r < 4; r++)
          Ts[colc * 40 + half * 16 + quad * 4 + r] = f2bf(acc[mt][nt2][r] + bb);
      }
      __syncthreads();
      #pragma unroll
      for (int it = 0; it < 2; it++) {
        int c = (tid >> 2) + 64 * it;
        int j = tid & 3;
        bf16x8 v = *(const bf16x8*)&Ts[c * 40 + j * 8];
        int tg = t20 + (j >> 1) * (BM / 2) + mt * 16 + (j & 1) * 8;
        *(bf16x8*)((u16*)Cp + ((size_t)b2 * 512 + n0 + c) * 1024 + tg) = v;
      }
      __syncthreads();
    }
    return;
  }

  #pragma unroll
  for (int nt2 = 0; nt2 < 4; nt2++) {
    int col = n0 + wn + nt2 * 16 + m;
    float bb = biasp ? biasp[col] : 0.f;
    #pragma unroll
    for (int mt = 0; mt < MT; mt++) {
      #pragma unroll
      for (int r = 0; r < 4; r++) {
        int row = m0 + wm + mt * 16 + quad * 4 + r;
        float v = acc[mt][nt2][r] + bb;
        if (out_mode == 1) {
          ((u16*)Cp)[(size_t)row * N + col] = f2bf(v);
        } else {
          ((float*)Cp)[(size_t)row * N + col] = v;
        }
      }
    }
  }
}

// ---------------- T projection only (2-phase double-buffered) ---------------
__global__ __launch_bounds__(256) void gemm_t8(
    const u16* __restrict__ A, const u16* __restrict__ Mt,
    const float* __restrict__ wbuf, u16* __restrict__ Tg)
{
  constexpr int TILE = 8192;
  __shared__ __align__(16) u16 smem[2 * TILE];
  const f32x4 zero4 = {0.f, 0.f, 0.f, 0.f};

  int h = blockIdx.z;
  const u16* Bp = Mt + (size_t)h * 262144;
  const float* biasp = wbuf + h * 512;
  u16* Og = Tg + (size_t)h * 4194304;

  int P = gridDim.x * gridDim.y;
  int p = blockIdx.x + gridDim.x * blockIdx.y;
  int f = (p & 7) * (P >> 3) + (p >> 3);
  int bx = f % gridDim.x, by = f / gridDim.x;

  int tid = threadIdx.x;
  int lane = tid & 63, wave = tid >> 6;
  int m = lane & 15, quad = lane >> 4;
  int wm = (wave >> 1) * 64, wn = (wave & 1) * 64;
  int m0 = by * 128, n0 = bx * 128;
  int lr = lane >> 2, lc = (lane & 3) << 3;

  auto stage = [&](int buf, int k0) {
    u16* As = smem + buf * TILE;
    u16* Bs = As + 4096;
    #pragma unroll
    for (int i = 0; i < 2; i++) {
      int rb = i * 64 + wave * 16;
      gl2lds16(A + (size_t)(m0 + rb + lr) * 512 + k0 + lc, &As[rb * 32]);
      gl2lds16(Bp + (size_t)(n0 + rb + lr) * 512 + k0 + lc, &Bs[rb * 32]);
    }
  };

  f32x4 acc[4][4];
  #pragma unroll
  for (int i = 0; i < 4; i++)
    #pragma unroll
    for (int j = 0; j < 4; j++) acc[i][j] = zero4;

  stage(0, 0);
  asm volatile("s_waitcnt vmcnt(0)" ::: "memory");
  __builtin_amdgcn_s_barrier();

  int cur = 0;
  for (int t = 0; t < 16; t++) {
    if (t + 1 < 16) stage(cur ^ 1, (t + 1) << 5);

    u16* As = smem + cur * TILE;
    u16* Bs = As + 4096;
    bf16x8 af[4], bfr[4];
    #pragma unroll
    for (int tt = 0; tt < 4; tt++) {
      af[tt]  = *(const bf16x8*)&As[(wm + tt * 16 + m) * 32 + quad * 8];
      bfr[tt] = *(const bf16x8*)&Bs[(wn + tt * 16 + m) * 32 + quad * 8];
    }
    #pragma unroll
    for (int mt = 0; mt < 4; mt++)
      #pragma unroll
      for (int nt = 0; nt < 4; nt++)
        acc[mt][nt] = __builtin_amdgcn_mfma_f32_16x16x32_bf16(af[mt], bfr[nt],
                                                              acc[mt][nt], 0, 0, 0);
    asm volatile("s_waitcnt vmcnt(0)" ::: "memory");
    __builtin_amdgcn_s_barrier();
    cur ^= 1;
  }

  #pragma unroll
  for (int nt = 0; nt < 4; nt++) {
    int col = n0 + wn + nt * 16 + m;
    float bb = biasp[col];
    #pragma unroll
    for (int mt = 0; mt < 4; mt++) {
      #pragma unroll
      for (int r = 0; r < 4; r++) {
        int row = m0 + wm + mt * 16 + quad * 4 + r;
        Og[(size_t)row * 512 + col] = f2bf(acc[mt][nt][r] + bb);
      }
    }
  }
}

// ---------------- flash attention (R9-proven, unchanged) --------------------
__global__ __launch_bounds__(256, 2) void attn_kernel(
    const u16* __restrict__ Tg, const u16* __restrict__ Krep,
    const u16* __restrict__ XT, u16* __restrict__ Oc, int h0)
{
  __shared__ __align__(16) u16 Kt[32][520];   // 33,280 B
  __shared__ __align__(16) u16 Vt[512 * 32];  // 32,768 B (chunk-XOR swizzled)
  __shared__ __align__(16) u16 Pl[64][40];    //  5,120 B
  __shared__ float lred[64];
  const f32x4 zero4 = {0.f, 0.f, 0.f, 0.f};
  const f32x16 zero16 = {0.f,0.f,0.f,0.f,0.f,0.f,0.f,0.f,
                         0.f,0.f,0.f,0.f,0.f,0.f,0.f,0.f};

  int b = blockIdx.x, qb = blockIdx.y, z = blockIdx.z;
  int h = h0 + z;

  size_t hb = ((size_t)z * 8 + b) * (size_t)(1024 * 512);
  const u16* Tp = Tg + hb;
  const u16* Kp = Krep + (size_t)b * (size_t)(1024 * 512); // x slab (K)
  const u16* Vp = XT + (size_t)b * (size_t)(512 * 1024);   // x^T slab ("V")

  int tid = threadIdx.x, lane = tid & 63, wave = tid >> 6;
  int m = lane & 15, quad = lane >> 4;         // QK roles (16x16)
  int l31 = lane & 31, hi = lane >> 5;         // PV roles (32x32)
  int qh = wave >> 1, dh = wave & 1;
  int q0 = qb * 64 + wave * 16;

  int vr = lane >> 2;
  int vc = (((lane & 3) ^ ((lane >> 3) & 3)) << 3);
  int vswz = (l31 >> 1) & 3;

  bf16x8 aq[16];
  #pragma unroll
  for (int kc = 0; kc < 16; kc++)
    aq[kc] = *(const bf16x8*)(Tp + (size_t)(q0 + m) * 512 + kc * 32 + quad * 8);

  f32x16 o[8];
  #pragma unroll
  for (int dt = 0; dt < 8; dt++) o[dt] = zero16;
  float lsum_acc[4] = {0.f, 0.f, 0.f, 0.f};
  const float scale = 0.04419417382415922f;

  // prologue: stage tile 0
  #pragma unroll
  for (int r = 0; r < 8; r++) {
    int row = wave * 8 + r;
    gl2lds16(Kp + (size_t)row * 512 + lane * 8, &Kt[row][0]);
  }
  #pragma unroll
  for (int j = 0; j < 8; j++) {
    int rb = wave * 128 + j * 16;
    gl2lds16(Vp + (size_t)(rb + vr) * 1024 + vc, &Vt[rb * 32]);
  }

  for (int kt = 0; kt < 32; kt++) {
    // ---- BAR-A: K(kt) complete everywhere ----
    asm volatile("s_waitcnt vmcnt(8)" ::: "memory");
    __builtin_amdgcn_sched_barrier(0);
    __builtin_amdgcn_s_barrier();
    __builtin_amdgcn_sched_barrier(0);

    // ---- QK ----
    f32x4 s0 = zero4, s1 = zero4;
    #pragma unroll
    for (int kc = 0; kc < 16; kc++) {
      bf16x8 bk0 = *(const bf16x8*)&Kt[m][kc * 32 + quad * 8];
      bf16x8 bk1 = *(const bf16x8*)&Kt[m + 16][kc * 32 + quad * 8];
      s0 = __builtin_amdgcn_mfma_f32_16x16x32_bf16(aq[kc], bk0, s0, 0, 0, 0);
      s1 = __builtin_amdgcn_mfma_f32_16x16x32_bf16(aq[kc], bk1, s1, 0, 0, 0);
    }

    // ---- exp, P write, per-lane lsum partial ----
    #pragma unroll
    for (int r = 0; r < 4; r++) {
      float e0 = __expf(s0[r] * scale);
      float e1 = __expf(s1[r] * scale);
      u16 p0 = f2bf(e0), p1 = f2bf(e1);
      int prow = wave * 16 + quad * 4 + r;
      Pl[prow][m] = p0;
      Pl[prow][m + 16] = p1;
      lsum_acc[r] += __uint_as_float((unsigned)p0 << 16) +
                     __uint_as_float((unsigned)p1 << 16);
    }

    // ---- BAR-B: V(kt) ready + P visible + Kt free ----
    asm volatile("s_waitcnt vmcnt(0) lgkmcnt(0)" ::: "memory");
    __builtin_amdgcn_sched_barrier(0);
    __builtin_amdgcn_s_barrier();
    __builtin_amdgcn_sched_barrier(0);

    if (kt < 31) {                 // K(kt+1) DMA flies under PV
      int kr1 = (kt + 1) * 32;
      #pragma unroll
      for (int r = 0; r < 8; r++) {
        int row = wave * 8 + r;
        gl2lds16(Kp + (size_t)(kr1 + row) * 512 + lane * 8, &Kt[row][0]);
      }
    }

    // ---- PV: 32x32x16 ----
    const u16* PlRow = &Pl[qh * 32 + l31][0];
    #pragma unroll
    for (int ks = 0; ks < 2; ks++) {
      bf16x8 pa = *(const bf16x8*)(PlRow + ks * 16 + hi * 8);
      #pragma unroll
      for (int dt = 0; dt < 8; dt++) {
        int rr = dh * 256 + dt * 32 + l31;
        int cc2 = (((ks * 2 + hi) ^ vswz) << 3);
        bf16x8 bv = *(const bf16x8*)&Vt[rr * 32 + cc2];
        o[dt] = __builtin_amdgcn_mfma_f32_32x32x16_bf16(pa, bv, o[dt], 0, 0, 0);
      }
    }

    // ---- BAR-C: PV reads delivered; Vt, Pl free ----
    asm volatile("s_waitcnt lgkmcnt(0)" ::: "memory");
    __builtin_amdgcn_sched_barrier(0);
    __builtin_amdgcn_s_barrier();
    __builtin_amdgcn_sched_barrier(0);

    if (kt < 31) {                 // V(kt+1) DMA flies under next QK
      int kr1 = (kt + 1) * 32;
      #pragma unroll
      for (int j = 0; j < 8; j++) {
        int rb = wave * 128 + j * 16;
        gl2lds16(Vp + (size_t)(rb + vr) * 1024 + kr1 + vc, &Vt[rb * 32]);
      }
    }
  }

  // ---- deferred lsum reduce (once, not per-kt) ----
  #pragma unroll
  for (int r = 0; r < 4; r++) {
    float t = lsum_acc[r];
    t += __shfl_xor(t, 1); t += __shfl_xor(t, 2);
    t += __shfl_xor(t, 4); t += __shfl_xor(t, 8);
    lsum_acc[r] = t;
  }
  if (m == 0) {
    #pragma unroll
    for (int r = 0; r < 4; r++)
      lred[wave * 16 + quad * 4 + r] = lsum_acc[r];
  }
  __syncthreads();

  float linv[16];
  #pragma unroll
  for (int g = 0; g < 4; g++) {
    float4 t = *(const float4*)&lred[qh * 32 + 8 * g + 4 * hi];
    linv[4 * g + 0] = 1.f / t.x; linv[4 * g + 1] = 1.f / t.y;
    linv[4 * g + 2] = 1.f / t.z; linv[4 * g + 3] = 1.f / t.w;
  }

  size_t obase = (size_t)b * 1024 + qb * 64 + qh * 32;
  #pragma unroll
  for (int dt = 0; dt < 8; dt++) {
    int dcol = dh * 256 + dt * 32 + l31;
    #pragma unroll
    for (int reg = 0; reg < 16; reg++) {
      int rowq = (reg & 3) + 8 * (reg >> 2) + 4 * hi;
      Oc[((obase + rowq) * 8 + h) * 512 + dcol] = f2bf(o[dt][reg] * linv[reg]);
    }
  }
}

// ---------------- fused partial-sum + bias + residual + LayerNorm ----------
__global__ __launch_bounds__(256) void ln_kernel(
    const float* __restrict__ xin0, const float* __restrict__ xin1,
    const float* __restrict__ bias, const float* __restrict__ res,
    const float* __restrict__ gam, const float* __restrict__ bet,
    float* __restrict__ outf, u16* __restrict__ outb, int do_relu)
{
  __shared__ float red[4];
  __shared__ float red2[4];
  int row = blockIdx.x, t = threadIdx.x;
  size_t base = (size_t)row * 512;
  float a0 = xin0[base + t] + bias[t];
  float a1 = xin0[base + 256 + t] + bias[256 + t];
  if (xin1) { a0 += xin1[base + t]; a1 += xin1[base + 256 + t]; }
  if (do_relu) { a0 = fmaxf(a0, 0.f); a1 = fmaxf(a1, 0.f); }
  a0 += res[base + t]; a1 += res[base + 256 + t];

  float s = a0 + a1;
  #pragma unroll
  for (int off = 32; off > 0; off >>= 1) s += __shfl_xor(s, off);
  if ((t & 63) == 0) red[t >> 6] = s;
  __syncthreads();
  float mu = (red[0] + red[1] + red[2] + red[3]) * (1.f / 512.f);

  float d0 = a0 - mu, d1 = a1 - mu;
  float q = d0 * d0 + d1 * d1;
  #pragma unroll
  for (int off = 32; off > 0; off >>= 1) q += __shfl_xor(q, off);
  if ((t & 63) == 0) red2[t >> 6] = q;
  __syncthreads();
  float var = (red2[0] + red2[1] + red2[2] + red2[3]) * (1.f / 512.f);
  float rs = rsqrtf(var + 1e-5f);

  float o0 = d0 * rs * gam[t] + bet[t];
  float o1 = d1 * rs * gam[t + 256] + bet[t + 256];
  outf[base + t] = o0;
  outf[base + 256 + t] = o1;
  if (outb) { outb[base + t] = f2bf(o0); outb[base + 256 + t] = f2bf(o1); }
}

// ---------------- host launch ----------------
extern "C" void kernel_launch(void* const* d_in, const int* in_sizes, int n_in,
                              void* d_out, int out_size, void* d_ws, size_t ws_size,
                              hipStream_t stream) {
  const float* x   = (const float*)d_in[0];
  const float* Wq  = (const float*)d_in[1];
  const float* bq  = (const float*)d_in[2];
  const float* Wk  = (const float*)d_in[3];
  const float* bk  = (const float*)d_in[4];  // cancels under softmax
  const float* Wv  = (const float*)d_in[5];
  const float* bv  = (const float*)d_in[6];
  const float* Wo  = (const float*)d_in[7];
  const float* bo  = (const float*)d_in[8];
  const float* g1  = (const float*)d_in[9];
  const float* bn1 = (const float*)d_in[10];
  const float* W1  = (const float*)d_in[11];
  const float* bf1 = (const float*)d_in[12];
  const float* W2  = (const float*)d_in[13];
  const float* bf2 = (const float*)d_in[14];
  const float* g2  = (const float*)d_in[15];
  const float* bn2 = (const float*)d_in[16];
  (void)bk;

  char* ws = (char*)d_ws;
  u16* Krep = (u16*)(ws + 0);            // x bf16 [8][1024][512] (K + GEMM A)
  u16* xb   = Krep;
  u16* Wqb = (u16*)(ws + 67108864);
  u16* Wkb = (u16*)(ws + 71303168);
  u16* Wvb = (u16*)(ws + 75497472);      // Wv bf16 (plain, 4 MB)
  u16* WoT = (u16*)(ws + 79691776);
  u16* W1T = (u16*)(ws + 83886080);
  u16* W2T = (u16*)(ws + 85983232);
  u16* Mt  = (u16*)(ws + 88080384);
  float* wbuf = (float*)(ws + 92274688);
  u16* cc  = (u16*)(ws + 92291072);      // 67.1 MB U = P.x  [B][T][H*D]
  u16* Tg  = (u16*)(ws + 159399936);     // 67.1 MB [H][B][1024][512]
  u16* XT  = (u16*)(ws + 226508800);     // 8.4 MB x^T per b [512][1024]
  u16* WvWoT = (u16*)(ws + 234897408);   // 4.2 MB (Wv.Wo)^T [512][4096]
  float* bop = (float*)(ws + 239091712); // 2 KB bo' = bo + sum bv.Wo
  float* y1f  = (float*)(ws + 159399936);
  u16*   y1b  = (u16*)(ws + 176177152);
  float* mha0 = (float*)(ws + 184565760);
  float* mha1 = (float*)(ws + 201342976);
  u16*   ff1  = (u16*)(ws + 92291072);   // over cc (dead after Wo)
  float* ff20 = (float*)(ws + 125845504);
  float* ff21 = (float*)(ws + 142622720);

  bo_fold<<<32, 256, 0, stream>>>(bv, Wo, bo, bop);
  cvt_all<<<18432, 256, 0, stream>>>(x, Krep, XT, Wq, Wk, Wv, Wo, W1, W2,
                                     Wqb, Wkb, Wvb, WoT, W1T, W2T);
  gemm_bt<128><<<dim3(4, 4, 8), 256, 0, stream>>>(Wkb, Wqb, nullptr, Mt,
      512, 512, 512, 512, 512, 262144LL, 0LL, 0LL, 524288LL, 1);
  wk_bias<<<1024, 256, 0, stream>>>(Wk, bq, wbuf);
  // WvWoT[e][h*512+d] = sum_c Wv_h[d][c] * Wo[h*512+c][e]
  gemm_bt<128><<<dim3(4, 4, 8), 256, 0, stream>>>(WoT, Wvb, nullptr, WvWoT,
      512, 4096, 512, 4096, 512, 512LL, 261632LL, 0LL, 1024LL, 1);

  gemm_t8<<<dim3(4, 64, 8), 256, 0, stream>>>(xb, Mt, wbuf, Tg);
  attn_kernel<<<dim3(8, 16, 8), 256, 0, stream>>>(Tg, Krep, XT, cc, 0);

  // Wo (folded): BM=128 tiles (m103 ladder: 128-row tiles >> 64-row)
  gemm_bt<128><<<dim3(4, 64, 2), 256, 0, stream>>>(cc, WvWoT, nullptr, mha0,
      8192, 512, 2048, 4096, 4096, 2048LL, 0LL, 0LL, 16777216LL, 0);
  ln_kernel<<<8192, 256, 0, stream>>>(mha0, mha1, bop, x, g1, bn1, y1f, y1b, 0);

  gemm_bt<128><<<dim3(16, 64, 1), 256, 0, stream>>>(y1b, W1T, bf1, ff1,
      8192, 2048, 512, 512, 512, 0LL, 0LL, 0LL, 0LL, 1);

  // W2: BM=128 tiles
  gemm_bt<128><<<dim3(4, 64, 2), 256, 0, stream>>>(ff1, W2T, nullptr, ff20,
      8192, 512, 1024, 2048, 2048, 1024LL, 0LL, 0LL, 16777216LL, 0);

  ln_kernel<<<8192, 256, 0, stream>>>(ff20, ff21, bf2, y1f, g2, bn2,
                                      (float*)d_out, nullptr, 1);
}